// Round 2
// 162.498 us; speedup vs baseline: 1.0167x; 1.0167x over previous
//
#include <hip/hip_runtime.h>

// TorchPatchNN: unfold(7x7) -> NN argmin over 8100 keys (D=147) -> gather value -> fold mean.
// Round 7 (= R6 with compile fix): pipe-overlap attack on k_nn + latency attack on k_fold.
//  - k_nn counters (R5): 4670 cyc/chunk vs components MFMA 1860 + LDS-read 1540 + VALU 520
//    => pipes run serially (lockstep LDS burst then MFMA burst). Fix: sched_group_barrier
//    pins {DS,MFMA} interleave per nt-group so LDS service overlaps the MFMA pipe; setprio(1)
//    around the compute phase arbitrates between the two independent co-resident blocks.
//  - sched_group_barrier counts must be LITERAL constants -> mt=0 iteration peeled by hand.
//  - Register wall: 128 VGPR + 128 AGPR = 256/wave exactly => NO new live values allowed
//    (any growth drops to 1 wave/SIMD). Interleave is schedule-only.
//  - k_fold: fully unrolled predicated 7x7: 49 independent u32 index loads, then 49
//    value loads with ILP; 216 blocks x 128 threads for TLP.
// Numerics unchanged (fp16 h + 2^-11*l split, 3 MFMA passes, tie-aware packed-u64 atomicMin).

#define NQ 8100
#define NK 8100
#define DD 147
#define HO 90
#define IMG 96
#define NCH 5                 // K chunks of 32 (160 padded K)
#define CST 262144            // f16 per chunk plane: 512 groups x 512
#define ARRN (NCH * CST)      // f16 per array

typedef _Float16 half8 __attribute__((ext_vector_type(8)));
typedef float f32x4 __attribute__((ext_vector_type(4)));

__device__ __forceinline__ void gld16(const _Float16* g, _Float16* l) {
    __builtin_amdgcn_global_load_lds(
        (const __attribute__((address_space(1))) unsigned int*)g,
        (__attribute__((address_space(3))) unsigned int*)l, 16, 0, 0);
}

// ---------------- prep: split Q/K into fp16 hi/lo (frag order) + key norms + init ---------
__global__ void k_prep(const float* __restrict__ query, const float* __restrict__ key,
                       _Float16* __restrict__ Qh, _Float16* __restrict__ Ql,
                       _Float16* __restrict__ Kh, _Float16* __restrict__ Kl,
                       float* __restrict__ kn, unsigned long long* __restrict__ fidx64) {
    const int bx = blockIdx.x;
    const bool isK = (blockIdx.y != 0);

    if (bx >= 640) {                      // fused k_kn region: 128 blocks on y==1
        if (!isK) return;
        int wave = threadIdx.x >> 6, lane = threadIdx.x & 63;
        int kb = ((bx - 640) * 4 + wave) * 16;
        for (int r = 0; r < 16; ++r) {
            int k = kb + r;
            float s = 0.f;
            if (k < NK)
                for (int d = lane; d < DD; d += 64) {
                    float v = key[k * DD + d];
                    s += v * v;
                }
#pragma unroll
            for (int off = 32; off; off >>= 1) s += __shfl_down(s, off, 64);
            if (lane == 0) {
                kn[k] = (k < NK) ? s : 1e30f;
                fidx64[k] = 0xFFFFFFFFFFFFFFFFull;   // ws re-poisoned every launch
            }
        }
        return;
    }

    int t = bx * 256 + threadIdx.x;             // 0 .. 163839 (ARRN/8)
    int c = t >> 15;                            // chunk
    int rem = t & 32767;                        // g*64 + lane
    int col = ((rem >> 6) << 4) + (rem & 15);   // g*16 + l15
    int quad = (rem >> 4) & 3;
    int kbase = c * 32 + quad * 8;

    float v[8];
#pragma unroll
    for (int j = 0; j < 8; ++j) {
        int k = kbase + j;
        float x = 0.f;
        if (k < DD && col < NQ) {
            if (isK) {
                x = key[col * DD + k];
            } else {
                int c3 = k / 49, r2 = k - 49 * c3;
                int rr = r2 / 7, ss = r2 - 7 * rr;
                int y = col / HO, xx = col - HO * y;
                x = query[(c3 * IMG + y + rr) * IMG + xx + ss];
            }
        }
        v[j] = x;
    }
    half8 h8, l8;
#pragma unroll
    for (int j = 0; j < 8; ++j) {
        _Float16 h = (_Float16)v[j];
        h8[j] = h;
        l8[j] = (_Float16)((v[j] - (float)h) * 2048.0f);
    }
    if (isK) {
        *(half8*)(Kh + t * 8) = h8;
        *(half8*)(Kl + t * 8) = l8;
    } else {
        *(half8*)(Qh + t * 8) = h8;
        *(half8*)(Ql + t * 8) = l8;
    }
}

// ---------------- main: split-f16 MFMA Q.K^T + fused argmin ----------------
__launch_bounds__(256, 2)
__global__ void k_nn(const _Float16* __restrict__ Qh, const _Float16* __restrict__ Ql,
                     const _Float16* __restrict__ Kh, const _Float16* __restrict__ Kl,
                     const float* __restrict__ kn, unsigned long long* __restrict__ out) {
    __shared__ __align__(16) char smem[65536];   // 2 x 32 KiB stage buffers (aliased epilogue)
    _Float16* sbase = (_Float16*)smem;

    const int tid = (int)threadIdx.x;
    const int wave = tid >> 6, lane = tid & 63;
    const int l15 = lane & 15, quad = lane >> 4;

    // XCD-aware swizzle: blockIdx%8 == XCD (round-robin heuristic). Each XCD gets a
    // 16qt x 32kt rectangle => Q 1.28 MB + K 2.56 MB = 3.84 MB <= 4 MiB L2.
    const int b = (int)blockIdx.x;
    const int xcd = b & 7;
    const int i = b >> 3;                         // 0..511 within XCD
    const int qt = (xcd >> 1) * 16 + (i & 15);
    const int kt = (xcd & 1) * 32 + (i >> 4);

    const int mbase = (wave >> 1) * 64;           // wave tile: 64x64 within 128x128
    const int nbase = (wave & 1) * 64;
    const int q0 = qt * 128, n0 = kt * 128;

    // per-wave staging source: wave 0->Qh,1->Ql,2->Kh,3->Kl
    const _Float16* gsrc = (wave == 0) ? Qh : (wave == 1) ? Ql : (wave == 2) ? Kh : Kl;
    const int gbase = ((wave < 2) ? qt : kt) * 8;
    const _Float16* gp0 = gsrc + gbase * 512 + lane * 8;
    _Float16* ldst0 = sbase + wave * 4096 + lane * 8;

    f32x4 acc0[4][4], acc1[4][4];
#pragma unroll
    for (int ii = 0; ii < 4; ++ii)
#pragma unroll
        for (int j = 0; j < 4; ++j) {
            acc0[ii][j] = (f32x4)0.f;
            acc1[ii][j] = (f32x4)0.f;
        }

    const int agrp = (mbase >> 4);
    const int bgrp = (nbase >> 4);

    // preamble: stage chunk 0 into buffer 0
#pragma unroll
    for (int grp = 0; grp < 8; ++grp)
        gld16(gp0 + grp * 512, ldst0 + grp * 512);

#pragma unroll
    for (int c = 0; c < NCH; ++c) {
        __syncthreads();   // drains vmcnt -> buf[c&1] ready for all waves
        if (c + 1 < NCH) { // prefetch next chunk into the other buffer (full compute cover)
            const _Float16* gp = gp0 + (c + 1) * CST;
            _Float16* ld = ldst0 + ((c + 1) & 1) * 16384;
#pragma unroll
            for (int grp = 0; grp < 8; ++grp)
                gld16(gp + grp * 512, ld + grp * 512);
        }

        const _Float16* sQh = sbase + (c & 1) * 16384;
        const _Float16* sQl = sQh + 4096;
        const _Float16* sKh = sQh + 8192;
        const _Float16* sKl = sQh + 12288;

        __builtin_amdgcn_s_setprio(1);
        half8 ah[4], al[4];
        // nt = 0: interleave A-frag loads with the first MFMA column.
        // sched_group_barrier pins {DS,MFMA} trickle so the LDS pipe overlaps the MFMA pipe
        // (R5 counters showed the two running serially: 1540 + 1860 cyc/chunk back-to-back).
        // NOTE: group-barrier counts must be literal constants -> mt=0 peeled by hand.
        {
            int boff = (bgrp + 0) * 512 + lane * 8;
            half8 bh = *(const half8*)(sKh + boff);
            half8 bl = *(const half8*)(sKl + boff);
            {   // mt = 0: 4 DS (bh, bl, ah[0], al[0]) + 3 MFMA
                int aoff = (agrp + 0) * 512 + lane * 8;
                ah[0] = *(const half8*)(sQh + aoff);
                al[0] = *(const half8*)(sQl + aoff);
                acc0[0][0] = __builtin_amdgcn_mfma_f32_16x16x32_f16(ah[0], bh, acc0[0][0], 0, 0, 0);
                acc1[0][0] = __builtin_amdgcn_mfma_f32_16x16x32_f16(ah[0], bl, acc1[0][0], 0, 0, 0);
                acc1[0][0] = __builtin_amdgcn_mfma_f32_16x16x32_f16(al[0], bh, acc1[0][0], 0, 0, 0);
                __builtin_amdgcn_sched_group_barrier(0x100, 4, 0); // DS_READ
                __builtin_amdgcn_sched_group_barrier(0x008, 3, 0); // MFMA
            }
#pragma unroll
            for (int mt = 1; mt < 4; ++mt) {   // 2 DS (ah[mt], al[mt]) + 3 MFMA each
                int aoff = (agrp + mt) * 512 + lane * 8;
                ah[mt] = *(const half8*)(sQh + aoff);
                al[mt] = *(const half8*)(sQl + aoff);
                acc0[mt][0] = __builtin_amdgcn_mfma_f32_16x16x32_f16(ah[mt], bh, acc0[mt][0], 0, 0, 0);
                acc1[mt][0] = __builtin_amdgcn_mfma_f32_16x16x32_f16(ah[mt], bl, acc1[mt][0], 0, 0, 0);
                acc1[mt][0] = __builtin_amdgcn_mfma_f32_16x16x32_f16(al[mt], bh, acc1[mt][0], 0, 0, 0);
                __builtin_amdgcn_sched_group_barrier(0x100, 2, 0); // DS_READ
                __builtin_amdgcn_sched_group_barrier(0x008, 3, 0); // MFMA
            }
        }
#pragma unroll
        for (int nt = 1; nt < 4; ++nt) {
            int boff = (bgrp + nt) * 512 + lane * 8;
            half8 bh = *(const half8*)(sKh + boff);
            half8 bl = *(const half8*)(sKl + boff);
#pragma unroll
            for (int mt = 0; mt < 4; ++mt) {
                acc0[mt][nt] = __builtin_amdgcn_mfma_f32_16x16x32_f16(ah[mt], bh, acc0[mt][nt], 0, 0, 0);
                acc1[mt][nt] = __builtin_amdgcn_mfma_f32_16x16x32_f16(ah[mt], bl, acc1[mt][nt], 0, 0, 0);
                acc1[mt][nt] = __builtin_amdgcn_mfma_f32_16x16x32_f16(al[mt], bh, acc1[mt][nt], 0, 0, 0);
            }
            __builtin_amdgcn_sched_group_barrier(0x100, 2, 0);  // DS_READ: bh,bl of this nt
            __builtin_amdgcn_sched_group_barrier(0x008, 12, 0); // MFMA: this nt's column
        }
        __builtin_amdgcn_s_setprio(0);
    }

    // epilogue: dist = kn - 2*(acc0 + acc1/2048); per-lane argmin over its 4 columns
    float knv[4];
    int nglob[4];
#pragma unroll
    for (int nt = 0; nt < 4; ++nt) {
        nglob[nt] = n0 + nbase + nt * 16 + l15;
        knv[nt] = kn[nglob[nt]];
    }
    __syncthreads();   // done with staging LDS; reuse for reduction
    float* redv = (float*)smem;            // [128][33] f32, pad stride kills bank conflicts
    int* redi = (int*)(smem + 17408);      // [128][33] i32

#pragma unroll
    for (int mt = 0; mt < 4; ++mt)
#pragma unroll
        for (int r = 0; r < 4; ++r) {
            float bv = 1e38f;
            int bn = 0x7fffffff;
#pragma unroll
            for (int nt = 0; nt < 4; ++nt) {   // ascending n within lane -> strict < ok
                float d = knv[nt] - 2.0f * (acc0[mt][nt][r] + acc1[mt][nt][r] * (1.0f / 2048.0f));
                if (d < bv) { bv = d; bn = nglob[nt]; }
            }
            int m = mbase + mt * 16 + quad * 4 + r;        // C layout: row = quad*4 + reg
            int cidx = (nbase >> 2) + l15;                 // 0..31
            redv[m * 33 + cidx] = bv;
            redi[m * 33 + cidx] = bn;
        }
    __syncthreads();

    if (tid < 128) {
        float bv = 1e38f;
        int bn = 0x7fffffff;
        for (int t2 = 0; t2 < 32; ++t2) {     // tie-aware compare (lanes interleave n)
            float v = redv[tid * 33 + t2];
            int n = redi[tid * 33 + t2];
            if (v < bv || (v == bv && n < bn)) { bv = v; bn = n; }
        }
        unsigned u = __float_as_uint(bv);
        u = (u & 0x80000000u) ? ~u : (u | 0x80000000u);   // order-preserving map
        unsigned long long pk = ((unsigned long long)u << 32) | (unsigned)bn;
        atomicMin(&out[q0 + tid], pk);
    }
}

// ---------------- gather + fold (overlap-add mean) ----------------
// Fully unrolled predicated 7x7: phase 1 issues 49 independent u32 index loads, phase 2
// issues 49 value loads with full ILP (R5 form had runtime loop bounds -> 49 serial
// dependent load chains per thread, latency-bound on a 108-block grid).
__global__ void k_fold(const float* __restrict__ value,
                       const unsigned long long* __restrict__ fidx64,
                       float* __restrict__ out) {
    int t = blockIdx.x * 128 + threadIdx.x;   // 3*96*96 = 27648
    if (t >= 3 * IMG * IMG) return;
    int c = t / (IMG * IMG);
    int rem = t % (IMG * IMG);
    int Y = rem / IMG, X = rem % IMG;
    const float* vbase = value + c * 49;
    const unsigned* fidx32 = (const unsigned*)fidx64;   // low word = row index

    int rows[49];
    bool oks[49];
#pragma unroll
    for (int i = 0; i < 7; ++i)
#pragma unroll
        for (int j = 0; j < 7; ++j) {
            int yy = Y - i, xx = X - j;
            bool ok = ((unsigned)yy < (unsigned)HO) && ((unsigned)xx < (unsigned)HO);
            int p = ok ? (yy * HO + xx) : 0;
            rows[i * 7 + j] = (int)fidx32[2 * p];
            oks[i * 7 + j] = ok;
        }
    float s = 0.f, cnt = 0.f;
#pragma unroll
    for (int i = 0; i < 7; ++i)
#pragma unroll
        for (int j = 0; j < 7; ++j) {
            int k = i * 7 + j;
            float v = vbase[rows[k] * DD + k];   // always in-bounds (row 0 when masked)
            if (oks[k]) { s += v; cnt += 1.f; }
        }
    out[t] = s / cnt;
}

extern "C" void kernel_launch(void* const* d_in, const int* in_sizes, int n_in,
                              void* d_out, int out_size, void* d_ws, size_t ws_size,
                              hipStream_t stream) {
    const float* query = (const float*)d_in[0];
    const float* key   = (const float*)d_in[1];
    const float* value = (const float*)d_in[2];
    float* out = (float*)d_out;

    _Float16* Qh = (_Float16*)d_ws;           // ARRN f16 each
    _Float16* Ql = Qh + ARRN;
    _Float16* Kh = Ql + ARRN;
    _Float16* Kl = Kh + ARRN;
    float* kn = (float*)(Kl + ARRN);          // 8192 f32
    unsigned long long* fidx64 = (unsigned long long*)(kn + 8192);   // 8192 u64

    dim3 gp(768, 2);   // 640 split blocks + 128 fused-kn blocks (y==1)
    k_prep<<<gp, 256, 0, stream>>>(query, key, Qh, Ql, Kh, Kl, kn, fidx64);
    k_nn<<<4096, 256, 0, stream>>>(Qh, Ql, Kh, Kl, kn, fidx64);
    k_fold<<<216, 128, 0, stream>>>(value, fidx64, out);
}

// Round 3
// 159.728 us; speedup vs baseline: 1.0343x; 1.0173x over previous
//
#include <hip/hip_runtime.h>

// TorchPatchNN: unfold(7x7) -> NN argmin over 8100 keys (D=147) -> gather value -> fold mean.
// Round 8: revert R7's sched_group_barrier pinning (regressed: forced DS->MFMA adjacency,
//  killed the compiler's frag-hoist burst schedule, VGPR 128->112, +12us). Back to the R5
//  compiler-scheduled inner loop. Keep:
//   - R7's unrolled k_fold (saved ~15us).
//   - setprio(1) around compute only (T5 alone): 2 independent blocks/CU = phase-diverse
//     regime where priority arbitration can pay (unlike barrier-locked lockstep).
//  New: epilogue stores packed u64 (order-preserving value,idx) directly -> branchless
//  u64-min reduction, 2 threads/row (256 threads) + shfl_xor combine. Lexicographic u64 min
//  == (value asc, idx asc) tie rule exactly.
//  Register wall: 128 VGPR + 128 AGPR = 256/wave == 2 waves/SIMD cap; no new live state.
// Numerics unchanged (fp16 h + 2^-11*l split, 3 MFMA passes, tie-aware packed-u64 atomicMin).

#define NQ 8100
#define NK 8100
#define DD 147
#define HO 90
#define IMG 96
#define NCH 5                 // K chunks of 32 (160 padded K)
#define CST 262144            // f16 per chunk plane: 512 groups x 512
#define ARRN (NCH * CST)      // f16 per array

typedef _Float16 half8 __attribute__((ext_vector_type(8)));
typedef float f32x4 __attribute__((ext_vector_type(4)));

__device__ __forceinline__ void gld16(const _Float16* g, _Float16* l) {
    __builtin_amdgcn_global_load_lds(
        (const __attribute__((address_space(1))) unsigned int*)g,
        (__attribute__((address_space(3))) unsigned int*)l, 16, 0, 0);
}

// ---------------- prep: split Q/K into fp16 hi/lo (frag order) + key norms + init ---------
__global__ void k_prep(const float* __restrict__ query, const float* __restrict__ key,
                       _Float16* __restrict__ Qh, _Float16* __restrict__ Ql,
                       _Float16* __restrict__ Kh, _Float16* __restrict__ Kl,
                       float* __restrict__ kn, unsigned long long* __restrict__ fidx64) {
    const int bx = blockIdx.x;
    const bool isK = (blockIdx.y != 0);

    if (bx >= 640) {                      // fused k_kn region: 128 blocks on y==1
        if (!isK) return;
        int wave = threadIdx.x >> 6, lane = threadIdx.x & 63;
        int kb = ((bx - 640) * 4 + wave) * 16;
        for (int r = 0; r < 16; ++r) {
            int k = kb + r;
            float s = 0.f;
            if (k < NK)
                for (int d = lane; d < DD; d += 64) {
                    float v = key[k * DD + d];
                    s += v * v;
                }
#pragma unroll
            for (int off = 32; off; off >>= 1) s += __shfl_down(s, off, 64);
            if (lane == 0) {
                kn[k] = (k < NK) ? s : 1e30f;
                fidx64[k] = 0xFFFFFFFFFFFFFFFFull;   // ws re-poisoned every launch
            }
        }
        return;
    }

    int t = bx * 256 + threadIdx.x;             // 0 .. 163839 (ARRN/8)
    int c = t >> 15;                            // chunk
    int rem = t & 32767;                        // g*64 + lane
    int col = ((rem >> 6) << 4) + (rem & 15);   // g*16 + l15
    int quad = (rem >> 4) & 3;
    int kbase = c * 32 + quad * 8;

    float v[8];
#pragma unroll
    for (int j = 0; j < 8; ++j) {
        int k = kbase + j;
        float x = 0.f;
        if (k < DD && col < NQ) {
            if (isK) {
                x = key[col * DD + k];
            } else {
                int c3 = k / 49, r2 = k - 49 * c3;
                int rr = r2 / 7, ss = r2 - 7 * rr;
                int y = col / HO, xx = col - HO * y;
                x = query[(c3 * IMG + y + rr) * IMG + xx + ss];
            }
        }
        v[j] = x;
    }
    half8 h8, l8;
#pragma unroll
    for (int j = 0; j < 8; ++j) {
        _Float16 h = (_Float16)v[j];
        h8[j] = h;
        l8[j] = (_Float16)((v[j] - (float)h) * 2048.0f);
    }
    if (isK) {
        *(half8*)(Kh + t * 8) = h8;
        *(half8*)(Kl + t * 8) = l8;
    } else {
        *(half8*)(Qh + t * 8) = h8;
        *(half8*)(Ql + t * 8) = l8;
    }
}

// ---------------- main: split-f16 MFMA Q.K^T + fused argmin ----------------
__launch_bounds__(256, 2)
__global__ void k_nn(const _Float16* __restrict__ Qh, const _Float16* __restrict__ Ql,
                     const _Float16* __restrict__ Kh, const _Float16* __restrict__ Kl,
                     const float* __restrict__ kn, unsigned long long* __restrict__ out) {
    __shared__ __align__(16) char smem[65536];   // 2 x 32 KiB stage buffers (aliased epilogue)
    _Float16* sbase = (_Float16*)smem;

    const int tid = (int)threadIdx.x;
    const int wave = tid >> 6, lane = tid & 63;
    const int l15 = lane & 15, quad = lane >> 4;

    // XCD-aware swizzle: blockIdx%8 == XCD (round-robin heuristic). Each XCD gets a
    // 16qt x 32kt rectangle => Q 1.28 MB + K 2.56 MB = 3.84 MB <= 4 MiB L2.
    const int b = (int)blockIdx.x;
    const int xcd = b & 7;
    const int i = b >> 3;                         // 0..511 within XCD
    const int qt = (xcd >> 1) * 16 + (i & 15);
    const int kt = (xcd & 1) * 32 + (i >> 4);

    const int mbase = (wave >> 1) * 64;           // wave tile: 64x64 within 128x128
    const int nbase = (wave & 1) * 64;
    const int q0 = qt * 128, n0 = kt * 128;

    // per-wave staging source: wave 0->Qh,1->Ql,2->Kh,3->Kl
    const _Float16* gsrc = (wave == 0) ? Qh : (wave == 1) ? Ql : (wave == 2) ? Kh : Kl;
    const int gbase = ((wave < 2) ? qt : kt) * 8;
    const _Float16* gp0 = gsrc + gbase * 512 + lane * 8;
    _Float16* ldst0 = sbase + wave * 4096 + lane * 8;

    f32x4 acc0[4][4], acc1[4][4];
#pragma unroll
    for (int ii = 0; ii < 4; ++ii)
#pragma unroll
        for (int j = 0; j < 4; ++j) {
            acc0[ii][j] = (f32x4)0.f;
            acc1[ii][j] = (f32x4)0.f;
        }

    const int agrp = (mbase >> 4);
    const int bgrp = (nbase >> 4);

    // preamble: stage chunk 0 into buffer 0
#pragma unroll
    for (int grp = 0; grp < 8; ++grp)
        gld16(gp0 + grp * 512, ldst0 + grp * 512);

#pragma unroll
    for (int c = 0; c < NCH; ++c) {
        __syncthreads();   // drains vmcnt -> buf[c&1] ready for all waves
        if (c + 1 < NCH) { // prefetch next chunk into the other buffer (full compute cover)
            const _Float16* gp = gp0 + (c + 1) * CST;
            _Float16* ld = ldst0 + ((c + 1) & 1) * 16384;
#pragma unroll
            for (int grp = 0; grp < 8; ++grp)
                gld16(gp + grp * 512, ld + grp * 512);
        }

        const _Float16* sQh = sbase + (c & 1) * 16384;
        const _Float16* sQl = sQh + 4096;
        const _Float16* sKh = sQh + 8192;
        const _Float16* sKl = sQh + 12288;

        // Compiler-scheduled burst (R5 form): hoisted frag reads + fine lgkmcnt is already
        // near-optimal (R7's pinned interleave regressed). setprio(1) = T5 only: prefer the
        // MFMA-phase wave over the other block's staging wave on the same SIMD.
        __builtin_amdgcn_s_setprio(1);
        half8 ah[4], al[4];
#pragma unroll
        for (int mt = 0; mt < 4; ++mt) {
            int aoff = (agrp + mt) * 512 + lane * 8;
            ah[mt] = *(const half8*)(sQh + aoff);
            al[mt] = *(const half8*)(sQl + aoff);
        }
#pragma unroll
        for (int nt = 0; nt < 4; ++nt) {
            int boff = (bgrp + nt) * 512 + lane * 8;
            half8 bh = *(const half8*)(sKh + boff);
            half8 bl = *(const half8*)(sKl + boff);
#pragma unroll
            for (int mt = 0; mt < 4; ++mt) {
                acc0[mt][nt] = __builtin_amdgcn_mfma_f32_16x16x32_f16(ah[mt], bh, acc0[mt][nt], 0, 0, 0);
                acc1[mt][nt] = __builtin_amdgcn_mfma_f32_16x16x32_f16(ah[mt], bl, acc1[mt][nt], 0, 0, 0);
                acc1[mt][nt] = __builtin_amdgcn_mfma_f32_16x16x32_f16(al[mt], bh, acc1[mt][nt], 0, 0, 0);
            }
        }
        __builtin_amdgcn_s_setprio(0);
    }

    // epilogue: dist = kn - 2*(acc0 + acc1/2048); per-lane argmin over its 4 columns.
    // Pack (value,idx) into order-preserving u64 at write time: lexicographic u64-min
    // == (value asc, idx asc) tie rule. Branchless scan, 2 threads per row.
    float knv[4];
    int nglob[4];
#pragma unroll
    for (int nt = 0; nt < 4; ++nt) {
        nglob[nt] = n0 + nbase + nt * 16 + l15;
        knv[nt] = kn[nglob[nt]];
    }
    __syncthreads();   // done with staging LDS; reuse for reduction
    unsigned long long* redu = (unsigned long long*)smem;   // [128][33] u64 (33.8 KiB)

#pragma unroll
    for (int mt = 0; mt < 4; ++mt)
#pragma unroll
        for (int r = 0; r < 4; ++r) {
            float bv = 1e38f;
            int bn = 0x7fffffff;
#pragma unroll
            for (int nt = 0; nt < 4; ++nt) {   // ascending n within lane -> strict < ok
                float d = knv[nt] - 2.0f * (acc0[mt][nt][r] + acc1[mt][nt][r] * (1.0f / 2048.0f));
                if (d < bv) { bv = d; bn = nglob[nt]; }
            }
            int m = mbase + mt * 16 + quad * 4 + r;        // C layout: row = quad*4 + reg
            int cidx = (nbase >> 2) + l15;                 // 0..31
            unsigned u = __float_as_uint(bv);
            u = (u & 0x80000000u) ? ~u : (u | 0x80000000u);   // order-preserving map
            redu[m * 33 + cidx] = ((unsigned long long)u << 32) | (unsigned)bn;
        }
    __syncthreads();

    {   // all 256 threads: 2 per row, 16 u64-min each, pair-combine via shfl
        int row = tid >> 1;
        int base = (tid & 1) * 16;
        unsigned long long best = 0xFFFFFFFFFFFFFFFFull;
        const unsigned long long* rp = redu + row * 33 + base;
#pragma unroll
        for (int t2 = 0; t2 < 16; ++t2) {
            unsigned long long v = rp[t2];
            best = (v < best) ? v : best;
        }
        unsigned long long other = __shfl_xor(best, 1, 64);
        best = (other < best) ? other : best;
        if (!(tid & 1)) atomicMin(&out[q0 + row], best);
    }
}

// ---------------- gather + fold (overlap-add mean) ----------------
// Fully unrolled predicated 7x7: phase 1 issues 49 independent u32 index loads, phase 2
// issues 49 value loads with full ILP (runtime-bound loop form had 49 serial dependent
// load chains per thread, latency-bound).
__global__ void k_fold(const float* __restrict__ value,
                       const unsigned long long* __restrict__ fidx64,
                       float* __restrict__ out) {
    int t = blockIdx.x * 128 + threadIdx.x;   // 3*96*96 = 27648
    if (t >= 3 * IMG * IMG) return;
    int c = t / (IMG * IMG);
    int rem = t % (IMG * IMG);
    int Y = rem / IMG, X = rem % IMG;
    const float* vbase = value + c * 49;
    const unsigned* fidx32 = (const unsigned*)fidx64;   // low word = row index

    int rows[49];
    bool oks[49];
#pragma unroll
    for (int i = 0; i < 7; ++i)
#pragma unroll
        for (int j = 0; j < 7; ++j) {
            int yy = Y - i, xx = X - j;
            bool ok = ((unsigned)yy < (unsigned)HO) && ((unsigned)xx < (unsigned)HO);
            int p = ok ? (yy * HO + xx) : 0;
            rows[i * 7 + j] = (int)fidx32[2 * p];
            oks[i * 7 + j] = ok;
        }
    float s = 0.f, cnt = 0.f;
#pragma unroll
    for (int i = 0; i < 7; ++i)
#pragma unroll
        for (int j = 0; j < 7; ++j) {
            int k = i * 7 + j;
            float v = vbase[rows[k] * DD + k];   // always in-bounds (row 0 when masked)
            if (oks[k]) { s += v; cnt += 1.f; }
        }
    out[t] = s / cnt;
}

extern "C" void kernel_launch(void* const* d_in, const int* in_sizes, int n_in,
                              void* d_out, int out_size, void* d_ws, size_t ws_size,
                              hipStream_t stream) {
    const float* query = (const float*)d_in[0];
    const float* key   = (const float*)d_in[1];
    const float* value = (const float*)d_in[2];
    float* out = (float*)d_out;

    _Float16* Qh = (_Float16*)d_ws;           // ARRN f16 each
    _Float16* Ql = Qh + ARRN;
    _Float16* Kh = Ql + ARRN;
    _Float16* Kl = Kh + ARRN;
    float* kn = (float*)(Kl + ARRN);          // 8192 f32
    unsigned long long* fidx64 = (unsigned long long*)(kn + 8192);   // 8192 u64

    dim3 gp(768, 2);   // 640 split blocks + 128 fused-kn blocks (y==1)
    k_prep<<<gp, 256, 0, stream>>>(query, key, Qh, Ql, Kh, Kl, kn, fidx64);
    k_nn<<<4096, 256, 0, stream>>>(Qh, Ql, Kh, Kl, kn, fidx64);
    k_fold<<<216, 128, 0, stream>>>(value, fidx64, out);
}

// Round 4
// 157.141 us; speedup vs baseline: 1.0514x; 1.0165x over previous
//
#include <hip/hip_runtime.h>

// TorchPatchNN: unfold(7x7) -> NN argmin over 8100 keys (D=147) -> gather value -> fold mean.
// Round 9: cut k_nn's LDS traffic in half — A-fragments (Qh/Ql) are stored frag-linear in
//  global, so load them directly global->VGPR per chunk (L2-hot: Q slice 2.6MB/XCD fits 4MiB
//  L2 under the existing swizzle). LDS now stages ONLY Kh/Kl (16KB/chunk, 2 bufs = 32KB).
//  R8 model: 4320 cyc/chunk = MFMA 1860 + LDS 1540 + VALU 500 mostly serial; removing the
//  A-side LDS round-trip drops LDS to ~770 cyc and halves staging issue.
//  A-loads issued FIRST after the barrier, K-prefetch after => MFMA waits vmcnt(4) and the
//  prefetch stays in flight across the compute phase (never drained mid-chunk).
//  Keep: setprio(1) compute-only (R8: +6us), u64-packed branchless epilogue, unrolled k_fold.
//  Register wall: ah/al were already 32 live VGPRs; source changed LDS->global, count same.
//  SQ_LDS_BANK_CONFLICT reads exactly 2^20 every round = saturated counter, not evidence.
// Numerics bit-identical (same operand values, same MFMA order, same tie rule).

#define NQ 8100
#define NK 8100
#define DD 147
#define HO 90
#define IMG 96
#define NCH 5                 // K chunks of 32 (160 padded K)
#define CST 262144            // f16 per chunk plane: 512 groups x 512
#define ARRN (NCH * CST)      // f16 per array

typedef _Float16 half8 __attribute__((ext_vector_type(8)));
typedef float f32x4 __attribute__((ext_vector_type(4)));

__device__ __forceinline__ void gld16(const _Float16* g, _Float16* l) {
    __builtin_amdgcn_global_load_lds(
        (const __attribute__((address_space(1))) unsigned int*)g,
        (__attribute__((address_space(3))) unsigned int*)l, 16, 0, 0);
}

// ---------------- prep: split Q/K into fp16 hi/lo (frag order) + key norms + init ---------
__global__ void k_prep(const float* __restrict__ query, const float* __restrict__ key,
                       _Float16* __restrict__ Qh, _Float16* __restrict__ Ql,
                       _Float16* __restrict__ Kh, _Float16* __restrict__ Kl,
                       float* __restrict__ kn, unsigned long long* __restrict__ fidx64) {
    const int bx = blockIdx.x;
    const bool isK = (blockIdx.y != 0);

    if (bx >= 640) {                      // fused k_kn region: 128 blocks on y==1
        if (!isK) return;
        int wave = threadIdx.x >> 6, lane = threadIdx.x & 63;
        int kb = ((bx - 640) * 4 + wave) * 16;
        for (int r = 0; r < 16; ++r) {
            int k = kb + r;
            float s = 0.f;
            if (k < NK)
                for (int d = lane; d < DD; d += 64) {
                    float v = key[k * DD + d];
                    s += v * v;
                }
#pragma unroll
            for (int off = 32; off; off >>= 1) s += __shfl_down(s, off, 64);
            if (lane == 0) {
                kn[k] = (k < NK) ? s : 1e30f;
                fidx64[k] = 0xFFFFFFFFFFFFFFFFull;   // ws re-poisoned every launch
            }
        }
        return;
    }

    int t = bx * 256 + threadIdx.x;             // 0 .. 163839 (ARRN/8)
    int c = t >> 15;                            // chunk
    int rem = t & 32767;                        // g*64 + lane
    int col = ((rem >> 6) << 4) + (rem & 15);   // g*16 + l15
    int quad = (rem >> 4) & 3;
    int kbase = c * 32 + quad * 8;

    float v[8];
#pragma unroll
    for (int j = 0; j < 8; ++j) {
        int k = kbase + j;
        float x = 0.f;
        if (k < DD && col < NQ) {
            if (isK) {
                x = key[col * DD + k];
            } else {
                int c3 = k / 49, r2 = k - 49 * c3;
                int rr = r2 / 7, ss = r2 - 7 * rr;
                int y = col / HO, xx = col - HO * y;
                x = query[(c3 * IMG + y + rr) * IMG + xx + ss];
            }
        }
        v[j] = x;
    }
    half8 h8, l8;
#pragma unroll
    for (int j = 0; j < 8; ++j) {
        _Float16 h = (_Float16)v[j];
        h8[j] = h;
        l8[j] = (_Float16)((v[j] - (float)h) * 2048.0f);
    }
    if (isK) {
        *(half8*)(Kh + t * 8) = h8;
        *(half8*)(Kl + t * 8) = l8;
    } else {
        *(half8*)(Qh + t * 8) = h8;
        *(half8*)(Ql + t * 8) = l8;
    }
}

// ---------------- main: split-f16 MFMA Q.K^T + fused argmin ----------------
__launch_bounds__(256, 2)
__global__ void k_nn(const _Float16* __restrict__ Qh, const _Float16* __restrict__ Ql,
                     const _Float16* __restrict__ Kh, const _Float16* __restrict__ Kl,
                     const float* __restrict__ kn, unsigned long long* __restrict__ out) {
    __shared__ __align__(16) char smem[65536];   // K staging 2 x 16 KiB; epilogue aliases
    _Float16* sbase = (_Float16*)smem;

    const int tid = (int)threadIdx.x;
    const int wave = tid >> 6, lane = tid & 63;
    const int l15 = lane & 15, quad = lane >> 4;

    // XCD-aware swizzle: blockIdx%8 == XCD (round-robin heuristic). Each XCD gets a
    // 16qt x 32kt rectangle => Q 2.6 MB (re-read direct) + streamed K stays L2-resident.
    const int b = (int)blockIdx.x;
    const int xcd = b & 7;
    const int i = b >> 3;                         // 0..511 within XCD
    const int qt = (xcd >> 1) * 16 + (i & 15);
    const int kt = (xcd & 1) * 32 + (i >> 4);

    const int mbase = (wave >> 1) * 64;           // wave tile: 64x64 within 128x128
    const int nbase = (wave & 1) * 64;
    const int q0 = qt * 128, n0 = kt * 128;

    // K staging: wave 0 -> Kh g0-3, wave 1 -> Kh g4-7, wave 2 -> Kl g0-3, wave 3 -> Kl g4-7
    const _Float16* gKsrc = (wave >= 2) ? Kl : Kh;
    const _Float16* gpK = gKsrc + (kt * 8 + (wave & 1) * 4) * 512 + lane * 8;
    _Float16* ldK = sbase + ((wave >= 2) ? 4096 : 0) + ((wave & 1) * 4) * 512 + lane * 8;

    // A-frag direct-load bases (frag-linear global layout)
    const int agrp = (mbase >> 4);
    const int bgrp = (nbase >> 4);
    const _Float16* gAh = Qh + (qt * 8 + agrp) * 512 + lane * 8;
    const _Float16* gAl = Ql + (qt * 8 + agrp) * 512 + lane * 8;

    f32x4 acc0[4][4], acc1[4][4];
#pragma unroll
    for (int ii = 0; ii < 4; ++ii)
#pragma unroll
        for (int j = 0; j < 4; ++j) {
            acc0[ii][j] = (f32x4)0.f;
            acc1[ii][j] = (f32x4)0.f;
        }

    // preamble: stage K chunk 0 into buffer 0
#pragma unroll
    for (int g = 0; g < 4; ++g)
        gld16(gpK + g * 512, ldK + g * 512);

#pragma unroll
    for (int c = 0; c < NCH; ++c) {
        __syncthreads();   // drains vmcnt -> K buf[c&1] ready for all waves
        // A frags direct from global (L2-hot). Issued FIRST so the MFMA wait is vmcnt(4)
        // with the K-prefetch (issued after) left outstanding across the compute phase.
        half8 ah[4], al[4];
#pragma unroll
        for (int mt = 0; mt < 4; ++mt) {
            ah[mt] = *(const half8*)(gAh + c * CST + mt * 512);
            al[mt] = *(const half8*)(gAl + c * CST + mt * 512);
        }
        if (c + 1 < NCH) { // prefetch next K chunk into the other buffer
            const _Float16* gp = gpK + (c + 1) * CST;
            _Float16* ld = ldK + ((c + 1) & 1) * 8192;
#pragma unroll
            for (int g = 0; g < 4; ++g)
                gld16(gp + g * 512, ld + g * 512);
        }

        const _Float16* sKh = sbase + (c & 1) * 8192;
        const _Float16* sKl = sKh + 4096;

        __builtin_amdgcn_s_setprio(1);
#pragma unroll
        for (int nt = 0; nt < 4; ++nt) {
            int boff = (bgrp + nt) * 512 + lane * 8;
            half8 bh = *(const half8*)(sKh + boff);
            half8 bl = *(const half8*)(sKl + boff);
#pragma unroll
            for (int mt = 0; mt < 4; ++mt) {
                acc0[mt][nt] = __builtin_amdgcn_mfma_f32_16x16x32_f16(ah[mt], bh, acc0[mt][nt], 0, 0, 0);
                acc1[mt][nt] = __builtin_amdgcn_mfma_f32_16x16x32_f16(ah[mt], bl, acc1[mt][nt], 0, 0, 0);
                acc1[mt][nt] = __builtin_amdgcn_mfma_f32_16x16x32_f16(al[mt], bh, acc1[mt][nt], 0, 0, 0);
            }
        }
        __builtin_amdgcn_s_setprio(0);
    }

    // epilogue: dist = kn - 2*(acc0 + acc1/2048); per-lane argmin over its 4 columns.
    // Pack (value,idx) into order-preserving u64: lexicographic u64-min == tie rule.
    float knv[4];
    int nglob[4];
#pragma unroll
    for (int nt = 0; nt < 4; ++nt) {
        nglob[nt] = n0 + nbase + nt * 16 + l15;
        knv[nt] = kn[nglob[nt]];
    }
    __syncthreads();   // done with staging LDS; reuse for reduction
    unsigned long long* redu = (unsigned long long*)smem;   // [128][33] u64 (33.8 KiB)

#pragma unroll
    for (int mt = 0; mt < 4; ++mt)
#pragma unroll
        for (int r = 0; r < 4; ++r) {
            float bv = 1e38f;
            int bn = 0x7fffffff;
#pragma unroll
            for (int nt = 0; nt < 4; ++nt) {   // ascending n within lane -> strict < ok
                float d = knv[nt] - 2.0f * (acc0[mt][nt][r] + acc1[mt][nt][r] * (1.0f / 2048.0f));
                if (d < bv) { bv = d; bn = nglob[nt]; }
            }
            int m = mbase + mt * 16 + quad * 4 + r;        // C layout: row = quad*4 + reg
            int cidx = (nbase >> 2) + l15;                 // 0..31
            unsigned u = __float_as_uint(bv);
            u = (u & 0x80000000u) ? ~u : (u | 0x80000000u);   // order-preserving map
            redu[m * 33 + cidx] = ((unsigned long long)u << 32) | (unsigned)bn;
        }
    __syncthreads();

    {   // all 256 threads: 2 per row, 16 u64-min each, pair-combine via shfl
        int row = tid >> 1;
        int base = (tid & 1) * 16;
        unsigned long long best = 0xFFFFFFFFFFFFFFFFull;
        const unsigned long long* rp = redu + row * 33 + base;
#pragma unroll
        for (int t2 = 0; t2 < 16; ++t2) {
            unsigned long long v = rp[t2];
            best = (v < best) ? v : best;
        }
        unsigned long long other = __shfl_xor(best, 1, 64);
        best = (other < best) ? other : best;
        if (!(tid & 1)) atomicMin(&out[q0 + row], best);
    }
}

// ---------------- gather + fold (overlap-add mean) ----------------
// Fully unrolled predicated 7x7: phase 1 issues 49 independent u32 index loads, phase 2
// issues 49 value loads with full ILP.
__global__ void k_fold(const float* __restrict__ value,
                       const unsigned long long* __restrict__ fidx64,
                       float* __restrict__ out) {
    int t = blockIdx.x * 128 + threadIdx.x;   // 3*96*96 = 27648
    if (t >= 3 * IMG * IMG) return;
    int c = t / (IMG * IMG);
    int rem = t % (IMG * IMG);
    int Y = rem / IMG, X = rem % IMG;
    const float* vbase = value + c * 49;
    const unsigned* fidx32 = (const unsigned*)fidx64;   // low word = row index

    int rows[49];
    bool oks[49];
#pragma unroll
    for (int i = 0; i < 7; ++i)
#pragma unroll
        for (int j = 0; j < 7; ++j) {
            int yy = Y - i, xx = X - j;
            bool ok = ((unsigned)yy < (unsigned)HO) && ((unsigned)xx < (unsigned)HO);
            int p = ok ? (yy * HO + xx) : 0;
            rows[i * 7 + j] = (int)fidx32[2 * p];
            oks[i * 7 + j] = ok;
        }
    float s = 0.f, cnt = 0.f;
#pragma unroll
    for (int i = 0; i < 7; ++i)
#pragma unroll
        for (int j = 0; j < 7; ++j) {
            int k = i * 7 + j;
            float v = vbase[rows[k] * DD + k];   // always in-bounds (row 0 when masked)
            if (oks[k]) { s += v; cnt += 1.f; }
        }
    out[t] = s / cnt;
}

extern "C" void kernel_launch(void* const* d_in, const int* in_sizes, int n_in,
                              void* d_out, int out_size, void* d_ws, size_t ws_size,
                              hipStream_t stream) {
    const float* query = (const float*)d_in[0];
    const float* key   = (const float*)d_in[1];
    const float* value = (const float*)d_in[2];
    float* out = (float*)d_out;

    _Float16* Qh = (_Float16*)d_ws;           // ARRN f16 each
    _Float16* Ql = Qh + ARRN;
    _Float16* Kh = Ql + ARRN;
    _Float16* Kl = Kh + ARRN;
    float* kn = (float*)(Kl + ARRN);          // 8192 f32
    unsigned long long* fidx64 = (unsigned long long*)(kn + 8192);   // 8192 u64

    dim3 gp(768, 2);   // 640 split blocks + 128 fused-kn blocks (y==1)
    k_prep<<<gp, 256, 0, stream>>>(query, key, Qh, Ql, Kh, Kl, kn, fidx64);
    k_nn<<<4096, 256, 0, stream>>>(Qh, Ql, Kh, Kl, kn, fidx64);
    k_fold<<<216, 128, 0, stream>>>(value, fidx64, out);
}